// Round 1
// baseline (96.787 us; speedup 1.0000x reference)
//
#include <hip/hip_runtime.h>

// Collapsed GAT (all fp32): x is broadcast over nodes => softmax of a constant
// row is exactly uniform => both attention layers drop out:
//   wh[b,k,h]  = sum_f x[b,-1,f] * W_heads[k,f,h]
//   hp[b,k,h]  = elu(wh[b,k,h])
//   who[b,c]   = sum_{k,h} hp[b,k,h] * W_out[k*64+h, c]
//   out[b,c]   = bf[c] + sum_c2 who[b,c2] * WfSum[c,c2],  WfSum[c,c2]=sum_n Wf[c,n*64+c2]
//
// R4: single fused kernel (96 blocks), replacing kA(192)+kB(32).
//   blocks 0..31  (batch b): Wh -> elu -> who[b,:] (absorbs old kB's W_out matvec),
//                            publish who to ws, __threadfence + agent release-add flag.
//   blocks 32..95 (row c):   stream Wf row (128 KB) -> rowsum rs[c2] in LDS,
//                            acquire-spin on flag (who-path overlaps the stream, so
//                            the wait is ~0), then out[b,c] = bf[c] + who[b,:].rs[:].
// Sync safety: 96 blocks x 4 waves << 256 CUs -> all co-resident; cross-XCD
// visibility via agent-scope atomics (per-XCD L2s are non-coherent). Flag lives in
// poisoned ws -> zeroed by a 4-byte hipMemsetAsync before the kernel (stream-ordered,
// graph-capturable).
// ws layout: who[32*64] floats (8 KB) | flag (uint, at byte 8192)

__global__ __launch_bounds__(256) void kFused(const float* __restrict__ Wf,
                                              const float* __restrict__ x,
                                              const float* __restrict__ W_heads,
                                              const float* __restrict__ W_out,
                                              const float* __restrict__ bias,
                                              float* __restrict__ ws,
                                              float* __restrict__ out) {
    float* whoG = ws;                                   // [32][64]
    unsigned int* flag = (unsigned int*)(ws + 2048);    // zeroed by memset
    const int t = threadIdx.x;

    __shared__ float s[16][64];   // reduction scratch (both paths)
    __shared__ float xl[128];     // who path: x[b,-1,:]
    __shared__ float hp[512];     // who path: elu(Wh)
    __shared__ float rs[64];      // Wf path: rowsum

    if (blockIdx.x < 32) {
        // ---------- batch block b: hp then who[b,:] ----------
        const int b = blockIdx.x;
        if (t < 32) {
            const float4 v = *reinterpret_cast<const float4*>(x + b * 1536 + 1408 + t * 4);
            xl[t * 4 + 0] = v.x; xl[t * 4 + 1] = v.y;
            xl[t * 4 + 2] = v.z; xl[t * 4 + 3] = v.w;
        }
        __syncthreads();
        // Wh: thread pair (fh=t&1) splits f; quad q=t>>1 owns (k=q>>4, hq=(q&15)*4).
        // Per wave at fixed f: 4 contiguous 256B segments -> fully coalesced float4.
        {
            const int fh = t & 1;
            const int q  = t >> 1;
            const int k  = q >> 4;
            const int hq = (q & 15) * 4;
            const float* wp = W_heads + k * 8192 + fh * 4096 + hq;
            float a0 = 0.f, a1 = 0.f, a2 = 0.f, a3 = 0.f;
#pragma unroll 8
            for (int f = 0; f < 64; ++f) {
                const float4 w = *reinterpret_cast<const float4*>(wp + f * 64);
                const float xv = xl[fh * 64 + f];
                a0 += xv * w.x; a1 += xv * w.y; a2 += xv * w.z; a3 += xv * w.w;
            }
            a0 += __shfl_xor(a0, 1); a1 += __shfl_xor(a1, 1);
            a2 += __shfl_xor(a2, 1); a3 += __shfl_xor(a3, 1);
            if (fh == 0) {
                const int j = k * 64 + hq;
                hp[j + 0] = (a0 > 0.f) ? a0 : expm1f(a0);
                hp[j + 1] = (a1 > 0.f) ? a1 : expm1f(a1);
                hp[j + 2] = (a2 > 0.f) ? a2 : expm1f(a2);
                hp[j + 3] = (a3 > 0.f) ? a3 : expm1f(a3);
            }
        }
        __syncthreads();
        // who[c] = sum_j hp[j] * W_out[j,c] — 16-way j-parallel, float4 over c
        {
            const int cq = t & 15;
            const int jg = t >> 4;
            float ax = 0.f, ay = 0.f, az = 0.f, aw = 0.f;
#pragma unroll 8
            for (int i = 0; i < 32; ++i) {
                const int j = jg + 16 * i;
                const float4 w = *reinterpret_cast<const float4*>(W_out + j * 64 + cq * 4);
                const float h = hp[j];
                ax += h * w.x; ay += h * w.y; az += h * w.z; aw += h * w.w;
            }
            s[jg][cq * 4 + 0] = ax; s[jg][cq * 4 + 1] = ay;
            s[jg][cq * 4 + 2] = az; s[jg][cq * 4 + 3] = aw;
        }
        __syncthreads();
        if (t < 64) {
            float sum = 0.f;
#pragma unroll
            for (int g = 0; g < 16; ++g) sum += s[g][t];
            whoG[b * 64 + t] = sum;
        }
        // publish: every thread flushes its own stores to the coherence point,
        // then one release-add signals arrival (device scope, cross-XCD safe)
        __threadfence();
        __syncthreads();
        if (t == 0)
            __hip_atomic_fetch_add(flag, 1u, __ATOMIC_RELEASE, __HIP_MEMORY_SCOPE_AGENT);
    } else {
        // ---------- Wf row block: rowsum, wait for who, final contraction ----------
        const int c = blockIdx.x - 32;
        const float* row = Wf + (size_t)c * 32768;
        const int p  = t & 15;    // c2 quad
        const int ng = t >> 4;    // n-group
        float ax = 0.f, ay = 0.f, az = 0.f, aw = 0.f;
#pragma unroll 8
        for (int i = 0; i < 32; ++i) {
            const float4 v = *reinterpret_cast<const float4*>(row + (ng + 16 * i) * 64 + p * 4);
            ax += v.x; ay += v.y; az += v.z; aw += v.w;
        }
        s[ng][p * 4 + 0] = ax; s[ng][p * 4 + 1] = ay;
        s[ng][p * 4 + 2] = az; s[ng][p * 4 + 3] = aw;
        __syncthreads();
        if (t < 64) {
            float sum = 0.f;
#pragma unroll
            for (int g = 0; g < 16; ++g) sum += s[g][t];
            rs[t] = sum;          // rs[c2] = sum_n Wf[c, n*64 + c2]
        }
        __syncthreads();
        // acquire-spin: who path runs concurrently, expected wait ~0
        while (__hip_atomic_load(flag, __ATOMIC_ACQUIRE, __HIP_MEMORY_SCOPE_AGENT) < 32u)
            __builtin_amdgcn_s_sleep(2);
        // out[b,c] = bf[c] + sum_c2 who[b,c2]*rs[c2]; 8 lanes per b, shfl-reduce
        const int b = t >> 3;
        const int g = t & 7;
        float acc = 0.f;
#pragma unroll
        for (int c2 = g * 8; c2 < g * 8 + 8; ++c2)
            acc += whoG[b * 64 + c2] * rs[c2];
        acc += __shfl_xor(acc, 1);
        acc += __shfl_xor(acc, 2);
        acc += __shfl_xor(acc, 4);
        if (g == 0) out[b * 64 + c] = acc + bias[c];
    }
}

extern "C" void kernel_launch(void* const* d_in, const int* in_sizes, int n_in,
                              void* d_out, int out_size, void* d_ws, size_t ws_size,
                              hipStream_t stream) {
    const float* x       = (const float*)d_in[0]; // (32,12,128)
    const float* W_heads = (const float*)d_in[1]; // (8,128,64)
    // d_in[2], d_in[3]: a1_heads/a2_heads — unused (softmax of constant is uniform)
    const float* W_out   = (const float*)d_in[4]; // (512,64)
    // d_in[5], d_in[6]: a1_out/a2_out — unused
    const float* Wf      = (const float*)d_in[7]; // (64,32768)
    const float* bias    = (const float*)d_in[8]; // (64,)
    float* ws = (float*)d_ws;

    // zero the arrival flag (ws is poisoned each iteration); 4 B, stream-ordered
    hipMemsetAsync((char*)d_ws + 8192, 0, 4, stream);
    kFused<<<96, 256, 0, stream>>>(Wf, x, W_heads, W_out, bias, ws, (float*)d_out);
}

// Round 2
// 81.470 us; speedup vs baseline: 1.1880x; 1.1880x over previous
//
#include <hip/hip_runtime.h>

// Collapsed GAT (all fp32): x is broadcast over nodes => softmax of a constant
// row is exactly uniform => both attention layers drop out:
//   wh[b,k,h]  = sum_f x[b,-1,f] * W_heads[k,f,h]
//   hp[b,k,h]  = elu(wh[b,k,h])
//   who[b,c]   = sum_{k,h} hp[b,k,h] * W_out[k*64+h, c]
//   out[b,c]   = bf[c] + sum_c2 who[b,c2] * WfSum[c,c2],  WfSum[c,c2]=sum_n Wf[c,n*64+c2]
//
// R5: two kernels, no handshake (R4's flag-spin cost +15us -> reverted).
//   kA (96 blocks):  0..63  Wf row c -> rowsum wsumT[c2][c]        (8 MB HBM stream)
//                    64..95 batch b: Wh -> elu -> who[b,:]          (overlaps for free)
//   kB (32 blocks):  out[b,c] = bf[c] + who[b,:]. wsumT[:,c]        (L2-resident, ~1us)
// ws layout: wsumT[c2*64+c] (16 KB) | who[b*64+c] (8 KB)

__global__ __launch_bounds__(256) void kA(const float* __restrict__ Wf,
                                          const float* __restrict__ x,
                                          const float* __restrict__ W_heads,
                                          const float* __restrict__ W_out,
                                          float* __restrict__ ws) {
    float* wsumT = ws;            // [64][64] transposed: [c2][c]
    float* whoG  = ws + 4096;     // [32][64]
    const int t = threadIdx.x;

    __shared__ float s[16][64];   // reduction scratch (both paths)

    if (blockIdx.x < 64) {
        // ---------- reduce one full row c of Wf (64 x 32768) over n ----------
        const int c = blockIdx.x;
        const float* row = Wf + (size_t)c * 32768;
        const int p  = t & 15;    // c2 quad
        const int ng = t >> 4;    // 0..15 n-group
        float ax = 0.f, ay = 0.f, az = 0.f, aw = 0.f;
#pragma unroll 8
        for (int i = 0; i < 32; ++i) {
            const float4 v = *reinterpret_cast<const float4*>(row + (ng + 16 * i) * 64 + p * 4);
            ax += v.x; ay += v.y; az += v.z; aw += v.w;
        }
        s[ng][p * 4 + 0] = ax; s[ng][p * 4 + 1] = ay;
        s[ng][p * 4 + 2] = az; s[ng][p * 4 + 3] = aw;
        __syncthreads();
        if (t < 64) {             // t = c2
            float sum = 0.f;
#pragma unroll
            for (int g = 0; g < 16; ++g) sum += s[g][t];
            wsumT[t * 64 + c] = sum;
        }
    } else {
        // ---------- batch block b: hp then who[b,:] ----------
        const int b = blockIdx.x - 64;
        __shared__ float xl[128];
        __shared__ float hp[512];
        if (t < 32) {
            const float4 v = *reinterpret_cast<const float4*>(x + b * 1536 + 1408 + t * 4);
            xl[t * 4 + 0] = v.x; xl[t * 4 + 1] = v.y;
            xl[t * 4 + 2] = v.z; xl[t * 4 + 3] = v.w;
        }
        __syncthreads();
        // Wh: thread pair (fh=t&1) splits f; quad q=t>>1 owns (k=q>>4, hq=(q&15)*4).
        // At fixed f the wave touches 4 contiguous 256B segments -> coalesced float4.
        {
            const int fh = t & 1;
            const int q  = t >> 1;
            const int k  = q >> 4;
            const int hq = (q & 15) * 4;
            const float* wp = W_heads + k * 8192 + fh * 4096 + hq;
            float a0 = 0.f, a1 = 0.f, a2 = 0.f, a3 = 0.f;
#pragma unroll 8
            for (int f = 0; f < 64; ++f) {
                const float4 w = *reinterpret_cast<const float4*>(wp + f * 64);
                const float xv = xl[fh * 64 + f];
                a0 += xv * w.x; a1 += xv * w.y; a2 += xv * w.z; a3 += xv * w.w;
            }
            a0 += __shfl_xor(a0, 1); a1 += __shfl_xor(a1, 1);
            a2 += __shfl_xor(a2, 1); a3 += __shfl_xor(a3, 1);
            if (fh == 0) {
                const int j = k * 64 + hq;
                hp[j + 0] = (a0 > 0.f) ? a0 : expm1f(a0);
                hp[j + 1] = (a1 > 0.f) ? a1 : expm1f(a1);
                hp[j + 2] = (a2 > 0.f) ? a2 : expm1f(a2);
                hp[j + 3] = (a3 > 0.f) ? a3 : expm1f(a3);
            }
        }
        __syncthreads();
        // who[c] = sum_j hp[j] * W_out[j,c] — 16-way j-parallel, float4 over c
        {
            const int cq = t & 15;
            const int jg = t >> 4;
            float ax = 0.f, ay = 0.f, az = 0.f, aw = 0.f;
#pragma unroll 8
            for (int i = 0; i < 32; ++i) {
                const int j = jg + 16 * i;
                const float4 w = *reinterpret_cast<const float4*>(W_out + j * 64 + cq * 4);
                const float h = hp[j];
                ax += h * w.x; ay += h * w.y; az += h * w.z; aw += h * w.w;
            }
            s[jg][cq * 4 + 0] = ax; s[jg][cq * 4 + 1] = ay;
            s[jg][cq * 4 + 2] = az; s[jg][cq * 4 + 3] = aw;
        }
        __syncthreads();
        if (t < 64) {
            float sum = 0.f;
#pragma unroll
            for (int g = 0; g < 16; ++g) sum += s[g][t];
            whoG[b * 64 + t] = sum;
        }
    }
}

// Final contraction: out[b,c] = bias[c] + sum_c2 who[b,c2] * wsumT[c2][c]
// Tiny: 256 B who + 16 KB wsumT per block, all L2-hit. Launch-overhead-bound.
__global__ __launch_bounds__(256) void kB(const float* __restrict__ bias,
                                          const float* __restrict__ ws,
                                          float* __restrict__ out) {
    const float* wsumT = ws;
    const float* whoG  = ws + 4096;
    const int b = blockIdx.x;
    const int t = threadIdx.x;

    __shared__ float who[64];
    __shared__ float red[256];
    if (t < 64) who[t] = whoG[b * 64 + t];
    __syncthreads();

    const int c  = t & 63;
    const int cg = t >> 6;        // 0..3, each owns 16 c2
    float acc = 0.f;
#pragma unroll
    for (int c2 = cg * 16; c2 < cg * 16 + 16; ++c2)
        acc += who[c2] * wsumT[c2 * 64 + c];
    red[t] = acc;
    __syncthreads();
    if (t < 64)
        out[b * 64 + t] = red[t] + red[t + 64] + red[t + 128] + red[t + 192] + bias[t];
}

extern "C" void kernel_launch(void* const* d_in, const int* in_sizes, int n_in,
                              void* d_out, int out_size, void* d_ws, size_t ws_size,
                              hipStream_t stream) {
    const float* x       = (const float*)d_in[0]; // (32,12,128)
    const float* W_heads = (const float*)d_in[1]; // (8,128,64)
    // d_in[2], d_in[3]: a1_heads/a2_heads — unused (softmax of constant is uniform)
    const float* W_out   = (const float*)d_in[4]; // (512,64)
    // d_in[5], d_in[6]: a1_out/a2_out — unused
    const float* Wf      = (const float*)d_in[7]; // (64,32768)
    const float* bias    = (const float*)d_in[8]; // (64,)
    float* ws = (float*)d_ws;     // 16 KB wsumT + 8 KB who

    kA<<<96, 256, 0, stream>>>(Wf, x, W_heads, W_out, ws);
    kB<<<32, 256, 0, stream>>>(bias, ws, (float*)d_out);
}